// Round 4
// baseline (391.747 us; speedup 1.0000x reference)
//
#include <hip/hip_runtime.h>
#include <math.h>

#define PI_F 3.14159265358979323846f
#define NB 8
#define NH 128
#define NL 4096
#define LF 2049   // NL/2 + 1

typedef float2 cpx;

__device__ __forceinline__ float gelu_exact(float x) {
  return 0.5f * x * (1.0f + erff(x * 0.70710678118654752f));
}
__device__ __forceinline__ cpx cadd(cpx a, cpx b) { return make_float2(a.x + b.x, a.y + b.y); }
__device__ __forceinline__ cpx csub(cpx a, cpx b) { return make_float2(a.x - b.x, a.y - b.y); }
__device__ __forceinline__ cpx cmul(cpx a, cpx b) {
  return make_float2(fmaf(a.x, b.x, -a.y * b.y), fmaf(a.x, b.y, a.y * b.x));
}
template <int SGN>
__device__ __forceinline__ cpx mulJ(cpx a) {  // multiply by SGN*i
  return (SGN < 0) ? make_float2(a.y, -a.x) : make_float2(-a.y, a.x);
}

// ---------------- precompute: C~ = F^-1 C, B~ = Bbar F, T = D F ----------------
// (libm sincosf here on purpose — these feed every downstream FLOP)
__global__ __launch_bounds__(128) void precomp1(
    const float* __restrict__ C2, const float* __restrict__ B2,
    const float* __restrict__ D,
    float* __restrict__ Bt, float* __restrict__ Ct, float* __restrict__ Tt) {
  int x = blockIdx.x, t = threadIdx.x, which = blockIdx.y;
  float sr = 0.f, si = 0.f;
  if (which == 0) {
    for (int k = 0; k < 128; ++k) {
      float th = -(float)((k * t) & 127) * (2.f * PI_F / 128.f);
      float s, c; sincosf(th, &s, &c);
      float br = B2[(x * 128 + k) * 2], bi = B2[(x * 128 + k) * 2 + 1];
      sr += br * c - bi * s; si += br * s + bi * c;
    }
    Bt[(t * 128 + x) * 2] = sr; Bt[(t * 128 + x) * 2 + 1] = si;
  } else if (which == 1) {
    for (int k = 0; k < 128; ++k) {
      float th = (float)((k * t) & 127) * (2.f * PI_F / 128.f);
      float s, c; sincosf(th, &s, &c);
      float cr = C2[(k * 128 + x) * 2], ci = C2[(k * 128 + x) * 2 + 1];
      sr += cr * c - ci * s; si += cr * s + ci * c;
    }
    Ct[(x * 128 + t) * 2] = sr * (1.f / 128.f);
    Ct[(x * 128 + t) * 2 + 1] = si * (1.f / 128.f);
  } else {
    for (int k = 0; k < 128; ++k) {
      float th = -(float)((k * t) & 127) * (2.f * PI_F / 128.f);
      float s, c; sincosf(th, &s, &c);
      float d = D[x * 128 + k];
      sr += d * c; si += d * s;
    }
    Tt[(x * 128 + t) * 2] = sr; Tt[(x * 128 + t) * 2 + 1] = si;
  }
}

__global__ __launch_bounds__(128) void precomp2(const float* __restrict__ Tt,
                                                float* __restrict__ Dt) {
  int q = blockIdx.x, h = threadIdx.x;
  float sr = 0.f, si = 0.f;
  for (int k = 0; k < 128; ++k) {
    float th = (float)((k * h) & 127) * (2.f * PI_F / 128.f);
    float s, c; sincosf(th, &s, &c);
    float tr = Tt[(k * 128 + q) * 2], ti = Tt[(k * 128 + q) * 2 + 1];
    sr += tr * c - ti * s; si += tr * s + ti * c;
  }
  Dt[(q * 128 + h) * 2] = sr * (1.f / 128.f);
  Dt[(q * 128 + h) * 2 + 1] = si * (1.f / 128.f);
}

// ---------------- register FFT-2048: radix 8*8*8*4, 256 threads ----------------
#define SW(k) ((k) ^ (((k) >> 4) & 31))

template <int SGN>
__device__ __forceinline__ void dft8(cpx a[8]) {
  cpx t0 = cadd(a[0], a[4]), u0 = csub(a[0], a[4]);
  cpx t1 = cadd(a[1], a[5]), u1 = csub(a[1], a[5]);
  cpx t2 = cadd(a[2], a[6]), u2 = csub(a[2], a[6]);
  cpx t3 = cadd(a[3], a[7]), u3 = csub(a[3], a[7]);
  cpx E0 = cadd(t0, t2), E2 = csub(t0, t2);
  cpx ju2 = mulJ<SGN>(u2);
  cpx E1 = cadd(u0, ju2), E3 = csub(u0, ju2);
  cpx O0 = cadd(t1, t3), O2 = csub(t1, t3);
  cpx ju3 = mulJ<SGN>(u3);
  cpx O1 = cadd(u1, ju3), O3 = csub(u1, ju3);
  const float r = 0.70710678118654752f;
  const float S = (float)SGN;
  cpx w1O1 = make_float2(r * (O1.x - S * O1.y), r * (O1.y + S * O1.x));
  cpx w3O3 = make_float2(r * (-O3.x - S * O3.y), r * (S * O3.x - O3.y));
  cpx jO2 = mulJ<SGN>(O2);
  a[0] = cadd(E0, O0);   a[4] = csub(E0, O0);
  a[1] = cadd(E1, w1O1); a[5] = csub(E1, w1O1);
  a[2] = cadd(E2, jO2);  a[6] = csub(E2, jO2);
  a[3] = cadd(E3, w3O3); a[7] = csub(E3, w3O3);
}

template <int SGN>
__device__ __forceinline__ void dft4(cpx b[4]) {
  cpx s0 = cadd(b[0], b[2]), d0 = csub(b[0], b[2]);
  cpx s1 = cadd(b[1], b[3]), d1 = csub(b[1], b[3]);
  cpx jd1 = mulJ<SGN>(d1);
  b[0] = cadd(s0, s1); b[2] = csub(s0, s1);
  b[1] = cadd(d0, jd1); b[3] = csub(d0, jd1);
}

__device__ __forceinline__ void twid8(cpx a[8], float ang) {
  float s, c; __sincosf(ang, &s, &c);
  cpx w1 = make_float2(c, s);
  cpx w2 = cmul(w1, w1), w3 = cmul(w2, w1), w4 = cmul(w2, w2);
  cpx w5 = cmul(w3, w2), w6 = cmul(w3, w3), w7 = cmul(w4, w3);
  a[1] = cmul(a[1], w1); a[2] = cmul(a[2], w2); a[3] = cmul(a[3], w3);
  a[4] = cmul(a[4], w4); a[5] = cmul(a[5], w5); a[6] = cmul(a[6], w6);
  a[7] = cmul(a[7], w7);
}

template <int SGN>
__device__ __forceinline__ void fft2048_core(cpx a[8], cpx* __restrict__ bufA,
                                             cpx* __restrict__ bufB, int t) {
  const float S = (float)SGN;
  dft8<SGN>(a);
  twid8(a, S * (2.f * PI_F / 2048.f) * (float)t);
#pragma unroll
  for (int p = 0; p < 8; ++p) bufA[p * 264 + t] = a[p];
  __syncthreads();
  int p = t >> 5, n1 = t & 31;
#pragma unroll
  for (int j = 0; j < 8; ++j) a[j] = bufA[p * 264 + n1 + 32 * j];
  dft8<SGN>(a);
  twid8(a, S * (2.f * PI_F / 256.f) * (float)n1);
#pragma unroll
  for (int q = 0; q < 8; ++q) bufB[p * 264 + q * 33 + n1] = a[q];
  __syncthreads();
  int q = (t >> 2) & 7, n2 = t & 3;
#pragma unroll
  for (int j = 0; j < 8; ++j) a[j] = bufB[p * 264 + q * 33 + n2 + 4 * j];
  dft8<SGN>(a);
  twid8(a, S * (2.f * PI_F / 32.f) * (float)n2);
#pragma unroll
  for (int d = 0; d < 8; ++d) bufA[p * 264 + q * 33 + 4 * d + n2] = a[d];
  __syncthreads();
#pragma unroll
  for (int h = 0; h < 2; ++h) {
    int d = 2 * n2 + h;
    cpx b[4];
#pragma unroll
    for (int m = 0; m < 4; ++m) b[m] = bufA[p * 264 + q * 33 + 4 * d + m];
    dft4<SGN>(b);
    int kb = p + 8 * q + 64 * d;
#pragma unroll
    for (int c = 0; c < 4; ++c) bufB[SW(kb + 512 * c)] = b[c];
  }
  __syncthreads();
}

// ---------------- forward rfft-4096 per (b,h) row ----------------
__global__ __launch_bounds__(256, 4) void fft_fwd(const float* __restrict__ u,
                                                  cpx* __restrict__ U) {
  __shared__ cpx bufA[2112], bufB[2112];
  int t = threadIdx.x;
  int row = blockIdx.x;
  const cpx* src = (const cpx*)(u + (size_t)row * NL);
  cpx a[8];
#pragma unroll
  for (int j = 0; j < 8; ++j) a[j] = src[t + 256 * j];
  fft2048_core<-1>(a, bufA, bufB, t);
  cpx* Urow = U + (size_t)row * LF;
#pragma unroll
  for (int r = 0; r < 4; ++r) {
    int k = t + (r << 8);
    if (k == 0) {
      cpx z0 = bufB[SW(0)];
      Urow[0] = make_float2(z0.x + z0.y, 0.f);
      Urow[2048] = make_float2(z0.x - z0.y, 0.f);
      cpx zN = bufB[SW(1024)];
      Urow[1024] = make_float2(zN.x, -zN.y);
    } else {
      cpx A = bufB[SW(k)];
      cpx M = bufB[SW(2048 - k)];
      float Br = M.x, Bi = -M.y;
      float sr = 0.5f * (A.x + Br), si = 0.5f * (A.y + Bi);
      float dr = 0.5f * (A.x - Br), di = 0.5f * (A.y - Bi);
      float th = (float)k * (PI_F / 2048.f);
      float sn, cs; __sincosf(th, &sn, &cs);
      float tr = cs * dr + sn * di;
      float ti = cs * di - sn * dr;
      Urow[k] = make_float2(sr + ti, si - tr);
      float A2r = M.x, A2i = M.y;
      float B2r = A.x, B2i = -A.y;
      float s2r = 0.5f * (A2r + B2r), s2i = 0.5f * (A2i + B2i);
      float d2r = 0.5f * (A2r - B2r), d2i = 0.5f * (A2i - B2i);
      float t2r = -cs * d2r + sn * d2i;
      float t2i = -cs * d2i - sn * d2r;
      Urow[2048 - k] = make_float2(s2r + t2i, s2i - t2r);
    }
  }
}

// ---------------- mixing: Y = C~ diag(kernel) B~ U + D~ U ----------------
// 256 threads = 16 groups of 16 lanes; lane = column (l), group owns an
// 8-wide p/h panel. LDS: U,V tiles 128 x 16 cpx (padded to 17) = 34.8 KB
// -> 4 blocks/CU. Acc 16 VGPR + ping-pong 32 VGPR: pipeline fits registers.
__device__ __forceinline__ void ld4(float4 d[4], const float4* __restrict__ p) {
#pragma unroll
  for (int kk = 0; kk < 4; ++kk) d[kk] = p[kk];
}
__device__ __forceinline__ void cmac4(const float4 m[4], float xr, float xi,
                                      float ar[8], float ai[8]) {
#pragma unroll
  for (int kk = 0; kk < 4; ++kk) {
    float4 v = m[kk];
    ar[2 * kk]     = fmaf(v.x, xr, fmaf(-v.y, xi, ar[2 * kk]));
    ai[2 * kk]     = fmaf(v.x, xi, fmaf( v.y, xr, ai[2 * kk]));
    ar[2 * kk + 1] = fmaf(v.z, xr, fmaf(-v.w, xi, ar[2 * kk + 1]));
    ai[2 * kk + 1] = fmaf(v.z, xi, fmaf( v.w, xr, ai[2 * kk + 1]));
  }
}

__global__ __launch_bounds__(256, 4) void mix_kernel(
    const cpx* __restrict__ U,
    const float* __restrict__ Bt, const float* __restrict__ Ct,
    const float* __restrict__ Dt, const float* __restrict__ Lam,
    cpx* __restrict__ Y) {
  __shared__ cpx sU[128][17], sV[128][17];
  int tid = threadIdx.x;
  int b = blockIdx.y;
  size_t ub = (size_t)b * NH * LF;

  if (blockIdx.x == 128) {  // Nyquist column l = 2048
    int t = tid;
    if (t < 128) sU[t][0] = U[ub + (size_t)t * LF + 2048];
    __syncthreads();
    if (t < 128) {
      float ar = 0.f, ai = 0.f;
      for (int q = 0; q < 128; ++q) {
        float ur = sU[q][0].x, ui = sU[q][0].y;
        float br = Bt[(q * 128 + t) * 2], bi = Bt[(q * 128 + t) * 2 + 1];
        ar = fmaf(br, ur, fmaf(-bi, ui, ar));
        ai = fmaf(br, ui, fmaf(bi, ur, ai));
      }
      float a = Lam[2 * t], bb = Lam[2 * t + 1];
      float dx = -a, dy = PI_F - bb;
      float inv = 1.f / (dx * dx + dy * dy);
      float kr = dx * inv, ki = -dy * inv;
      sV[t][0] = make_float2(kr * ar - ki * ai, kr * ai + ki * ar);
    }
    __syncthreads();
    if (t < 128) {
      float ar = 0.f, ai = 0.f;
      for (int q = 0; q < 128; ++q) {
        float ur = sU[q][0].x, ui = sU[q][0].y;
        float vr = sV[q][0].x, vi = sV[q][0].y;
        float cr = Ct[(q * 128 + t) * 2], ci = Ct[(q * 128 + t) * 2 + 1];
        float dr = Dt[(q * 128 + t) * 2], di = Dt[(q * 128 + t) * 2 + 1];
        ar += cr * vr - ci * vi + dr * ur - di * ui;
        ai += cr * vi + ci * vr + dr * ui + di * ur;
      }
      Y[ub + (size_t)t * LF + 2048] = make_float2(ar, ai);
    }
    return;
  }

  int lane = tid & 15, g = tid >> 4;   // 16 groups of 16 lanes
  int l = blockIdx.x * 16 + lane;      // l <= 2047 always valid
#pragma unroll
  for (int rep = 0; rep < 8; ++rep) {
    int q = rep * 16 + g;
    sU[q][lane] = U[ub + (size_t)q * LF + l];
  }
  __syncthreads();
  float omega = (float)l * (PI_F / 2048.f);

  float ar[8], ai[8];
  // ---- pass 1: V = B~ U (panel p0..p0+7), prefetch-1 pipeline ----
  {
#pragma unroll
    for (int k = 0; k < 8; ++k) { ar[k] = 0.f; ai[k] = 0.f; }
    const float4* base = (const float4*)Bt + g * 4;  // + q*64 per row
    float4 e[4], o[4];
    ld4(e, base);
#pragma unroll 1
    for (int q = 0; q < 128; q += 2) {
      ld4(o, base + (q + 1) * 64);
      cpx u0 = sU[q][lane];
      cmac4(e, u0.x, u0.y, ar, ai);
      ld4(e, base + ((q + 2) & 127) * 64);
      cpx u1 = sU[q + 1][lane];
      cmac4(o, u1.x, u1.y, ar, ai);
    }
    int p0 = g * 8;
#pragma unroll
    for (int k = 0; k < 8; ++k) {
      int p = p0 + k;
      float a = Lam[2 * p], bb = Lam[2 * p + 1];
      float dx = -a, dy = omega - bb;
      float inv = 1.f / (dx * dx + dy * dy);
      float kr = dx * inv, ki = -dy * inv;  // 1/(i*omega - lambda)
      sV[p][lane] = make_float2(kr * ar[k] - ki * ai[k], kr * ai[k] + ki * ar[k]);
    }
  }
  __syncthreads();

  // ---- pass 2a: Y = C~ V ----
  {
#pragma unroll
    for (int k = 0; k < 8; ++k) { ar[k] = 0.f; ai[k] = 0.f; }
    const float4* base = (const float4*)Ct + g * 4;
    float4 e[4], o[4];
    ld4(e, base);
#pragma unroll 1
    for (int q = 0; q < 128; q += 2) {
      ld4(o, base + (q + 1) * 64);
      cpx v0 = sV[q][lane];
      cmac4(e, v0.x, v0.y, ar, ai);
      ld4(e, base + ((q + 2) & 127) * 64);
      cpx v1 = sV[q + 1][lane];
      cmac4(o, v1.x, v1.y, ar, ai);
    }
  }
  // ---- pass 2b: Y += D~ U ----
  {
    const float4* base = (const float4*)Dt + g * 4;
    float4 e[4], o[4];
    ld4(e, base);
#pragma unroll 1
    for (int q = 0; q < 128; q += 2) {
      ld4(o, base + (q + 1) * 64);
      cpx u0 = sU[q][lane];
      cmac4(e, u0.x, u0.y, ar, ai);
      ld4(e, base + ((q + 2) & 127) * 64);
      cpx u1 = sU[q + 1][lane];
      cmac4(o, u1.x, u1.y, ar, ai);
    }
  }
  int h0 = g * 8;
#pragma unroll
  for (int k = 0; k < 8; ++k) {
    Y[ub + (size_t)(h0 + k) * LF + l] = make_float2(ar[k], ai[k]);
  }
}

// ---------------- inverse rfft-4096 per (b,h) row, fused exact GELU ----------------
__global__ __launch_bounds__(256, 4) void fft_inv_gelu(const cpx* __restrict__ Y,
                                                       float* __restrict__ out) {
  __shared__ cpx bufA[2112], bufB[2112];
  int t = threadIdx.x;
  int row = blockIdx.x;
  const cpx* Yrow = Y + (size_t)row * LF;
#pragma unroll
  for (int r = 0; r < 4; ++r) {
    int k = t + (r << 8);
    if (k == 0) {
      float y0 = Yrow[0].x;     // Im discarded (pocketfft irfft semantics)
      float yN = Yrow[2048].x;
      bufB[SW(0)] = make_float2(0.5f * (y0 + yN), 0.5f * (y0 - yN));
      cpx z = Yrow[1024];
      bufB[SW(1024)] = make_float2(z.x, -z.y);
    } else {
      cpx A = Yrow[k];
      cpx M = Yrow[2048 - k];
      float Br = M.x, Bi = -M.y;
      float sr = 0.5f * (A.x + Br), si = 0.5f * (A.y + Bi);
      float dr = 0.5f * (A.x - Br), di = 0.5f * (A.y - Bi);
      float th = (float)k * (PI_F / 2048.f);
      float sn, cs; __sincosf(th, &sn, &cs);
      float e1 = cs * di + sn * dr;
      float e2 = cs * dr - sn * di;
      bufB[SW(k)] = make_float2(sr - e1, si + e2);
      bufB[SW(2048 - k)] = make_float2(sr + e1, -si + e2);
    }
  }
  __syncthreads();
  cpx a[8];
#pragma unroll
  for (int j = 0; j < 8; ++j) a[j] = bufB[SW(t + 256 * j)];
  fft2048_core<1>(a, bufA, bufB, t);
  float2* dst = (float2*)(out + (size_t)row * NL);
  const float sc = 1.f / 2048.f;
#pragma unroll
  for (int r = 0; r < 8; ++r) {
    int n = t + (r << 8);
    cpx z = bufB[SW(n)];
    dst[n] = make_float2(gelu_exact(z.x * sc), gelu_exact(z.y * sc));
  }
}

extern "C" void kernel_launch(void* const* d_in, const int* in_sizes, int n_in,
                              void* d_out, int out_size, void* d_ws, size_t ws_size,
                              hipStream_t stream) {
  const float* u   = (const float*)d_in[0];
  const float* C2  = (const float*)d_in[1];
  const float* B2  = (const float*)d_in[2];
  const float* D   = (const float*)d_in[3];
  const float* Lam = (const float*)d_in[4];
  float* out = (float*)d_out;
  float* ws = (float*)d_ws;

  const size_t nUc = (size_t)NB * NH * LF;   // complex elements per plane
  cpx *U, *Yp;
  float* Bt;
  size_t need_full = (4 * nUc + 4 * 32768) * sizeof(float);
  if (ws_size >= need_full) {
    U = (cpx*)ws;
    Yp = U + nUc;
    Bt = ws + 4 * nUc;
  } else {
    // Alias Y onto U: each (b,l) column is fully read into LDS by its owning
    // mix block before that block writes Y to the same column.
    U = (cpx*)ws;
    Yp = U;
    Bt = ws + 2 * nUc;
  }
  float* Ct = Bt + 32768;
  float* Dt = Ct + 32768;
  float* Tt = Dt + 32768;

  precomp1<<<dim3(128, 3), 128, 0, stream>>>(C2, B2, D, Bt, Ct, Tt);
  precomp2<<<128, 128, 0, stream>>>(Tt, Dt);
  fft_fwd<<<NB * NH, 256, 0, stream>>>(u, U);
  mix_kernel<<<dim3(129, NB), 256, 0, stream>>>(U, Bt, Ct, Dt, Lam, Yp);
  fft_inv_gelu<<<NB * NH, 256, 0, stream>>>(Yp, out);
}

// Round 5
// 178.946 us; speedup vs baseline: 2.1892x; 2.1892x over previous
//
#include <hip/hip_runtime.h>
#include <math.h>

#define PI_F 3.14159265358979323846f
#define NB 8
#define NH 128
#define NL 4096
#define LF 2049    // NL/2 + 1
#define WB 2064    // padded per-batch column width (>=2049, mult of 16)
#define NT 16512   // WB * NB = total GEMM columns (= 258 * 64)

typedef float2 cpx;
typedef __attribute__((ext_vector_type(8))) short bf8v;   // 8 bf16 in 4 VGPRs
typedef __attribute__((ext_vector_type(4))) float f4;     // MFMA acc

#define MFMA16(a, b, c) __builtin_amdgcn_mfma_f32_16x16x32_bf16(a, b, c, 0, 0, 0)

__device__ __forceinline__ float gelu_exact(float x) {
  return 0.5f * x * (1.0f + erff(x * 0.70710678118654752f));
}
__device__ __forceinline__ unsigned short f2bf(float f) {
  unsigned int x = __float_as_uint(f);
  return (unsigned short)((x + 0x7FFFu + ((x >> 16) & 1u)) >> 16);
}
__device__ __forceinline__ float bf2f(unsigned short h) {
  return __uint_as_float((unsigned int)h << 16);
}
__device__ __forceinline__ cpx cadd(cpx a, cpx b) { return make_float2(a.x + b.x, a.y + b.y); }
__device__ __forceinline__ cpx csub(cpx a, cpx b) { return make_float2(a.x - b.x, a.y - b.y); }
__device__ __forceinline__ cpx cmul(cpx a, cpx b) {
  return make_float2(fmaf(a.x, b.x, -a.y * b.y), fmaf(a.x, b.y, a.y * b.x));
}
template <int SGN>
__device__ __forceinline__ cpx mulJ(cpx a) {
  return (SGN < 0) ? make_float2(a.y, -a.x) : make_float2(-a.y, a.x);
}

// ---------------- precompute: C~ = F^-1 C, B~ = Bbar F, T = D F ----------------
// LDS root table: 128 libm sincosf per block instead of 16384.
__global__ __launch_bounds__(128) void precomp1(
    const float* __restrict__ C2, const float* __restrict__ B2,
    const float* __restrict__ D,
    float* __restrict__ Bt, float* __restrict__ Ct, float* __restrict__ Tt) {
  __shared__ float rc[128], rs[128];
  int x = blockIdx.x, t = threadIdx.x, which = blockIdx.y;
  { float s, c; sincosf(-(2.f * PI_F / 128.f) * (float)t, &s, &c); rc[t] = c; rs[t] = s; }
  __syncthreads();
  float sr = 0.f, si = 0.f;
  if (which == 0) {
    for (int k = 0; k < 128; ++k) {
      int j = (k * t) & 127; float c = rc[j], s = rs[j];
      float br = B2[(x * 128 + k) * 2], bi = B2[(x * 128 + k) * 2 + 1];
      sr += br * c - bi * s; si += br * s + bi * c;
    }
    Bt[(t * 128 + x) * 2] = sr; Bt[(t * 128 + x) * 2 + 1] = si;
  } else if (which == 1) {
    for (int k = 0; k < 128; ++k) {
      int j = (k * t) & 127; float c = rc[j], s = -rs[j];  // e^{+i theta}
      float cr = C2[(k * 128 + x) * 2], ci = C2[(k * 128 + x) * 2 + 1];
      sr += cr * c - ci * s; si += cr * s + ci * c;
    }
    Ct[(x * 128 + t) * 2] = sr * (1.f / 128.f);
    Ct[(x * 128 + t) * 2 + 1] = si * (1.f / 128.f);
  } else {
    for (int k = 0; k < 128; ++k) {
      int j = (k * t) & 127; float c = rc[j], s = rs[j];
      float d = D[x * 128 + k];
      sr += d * c; si += d * s;
    }
    Tt[(x * 128 + t) * 2] = sr; Tt[(x * 128 + t) * 2 + 1] = si;
  }
}

__global__ __launch_bounds__(128) void precomp2(const float* __restrict__ Tt,
                                                float* __restrict__ Dt) {
  __shared__ float rc[128], rs[128];
  int q = blockIdx.x, h = threadIdx.x;
  { float s, c; sincosf(-(2.f * PI_F / 128.f) * (float)h, &s, &c); rc[h] = c; rs[h] = s; }
  __syncthreads();
  float sr = 0.f, si = 0.f;
  for (int k = 0; k < 128; ++k) {
    int j = (k * h) & 127; float c = rc[j], s = -rs[j];    // e^{+i theta}
    float tr = Tt[(k * 128 + q) * 2], ti = Tt[(k * 128 + q) * 2 + 1];
    sr += tr * c - ti * s; si += tr * s + ti * c;
  }
  Dt[(q * 128 + h) * 2] = sr * (1.f / 128.f);
  Dt[(q * 128 + h) * 2 + 1] = si * (1.f / 128.f);
}

// ---------------- pack real GEMM matrices Mb (256x256), Mc (256x512), bf16 hi/lo ----------------
// Row 2p = Re-row, 2p+1 = Im-row; Mb cols 2q/2q+1 multiply (Ur,Ui); Mc cols: [0,256)=V', [256,512)=U.
__global__ __launch_bounds__(256) void pack_mats(
    const float* __restrict__ Bt, const float* __restrict__ Ct, const float* __restrict__ Dt,
    unsigned short* __restrict__ Mbh, unsigned short* __restrict__ Mbl,
    unsigned short* __restrict__ Mch, unsigned short* __restrict__ Mcl) {
  int r = blockIdx.x, t = threadIdx.x;
  int p = r >> 1, par = r & 1;
  {
    int q = t >> 1, cq = t & 1;
    float br = Bt[(q * 128 + p) * 2], bi = Bt[(q * 128 + p) * 2 + 1];
    float v = par == 0 ? (cq == 0 ? br : -bi) : (cq == 0 ? bi : br);
    unsigned short h = f2bf(v);
    Mbh[r * 256 + t] = h; Mbl[r * 256 + t] = f2bf(v - bf2f(h));
  }
  for (int cc = 0; cc < 2; ++cc) {
    int c = t + cc * 256;
    float v;
    if (c < 256) {
      int pp = c >> 1, cq = c & 1;
      float cr = Ct[(pp * 128 + p) * 2], ci = Ct[(pp * 128 + p) * 2 + 1];
      v = par == 0 ? (cq == 0 ? cr : -ci) : (cq == 0 ? ci : cr);
    } else {
      int qq = (c - 256) >> 1, cq = c & 1;
      float dr = Dt[(qq * 128 + p) * 2], di = Dt[(qq * 128 + p) * 2 + 1];
      v = par == 0 ? (cq == 0 ? dr : -di) : (cq == 0 ? di : dr);
    }
    unsigned short h = f2bf(v);
    Mch[r * 512 + c] = h; Mcl[r * 512 + c] = f2bf(v - bf2f(h));
  }
}

// ---------------- register FFT-2048: radix 8*8*8*4, 256 threads ----------------
#define SW(k) ((k) ^ (((k) >> 4) & 31))

template <int SGN>
__device__ __forceinline__ void dft8(cpx a[8]) {
  cpx t0 = cadd(a[0], a[4]), u0 = csub(a[0], a[4]);
  cpx t1 = cadd(a[1], a[5]), u1 = csub(a[1], a[5]);
  cpx t2 = cadd(a[2], a[6]), u2 = csub(a[2], a[6]);
  cpx t3 = cadd(a[3], a[7]), u3 = csub(a[3], a[7]);
  cpx E0 = cadd(t0, t2), E2 = csub(t0, t2);
  cpx ju2 = mulJ<SGN>(u2);
  cpx E1 = cadd(u0, ju2), E3 = csub(u0, ju2);
  cpx O0 = cadd(t1, t3), O2 = csub(t1, t3);
  cpx ju3 = mulJ<SGN>(u3);
  cpx O1 = cadd(u1, ju3), O3 = csub(u1, ju3);
  const float r = 0.70710678118654752f;
  const float S = (float)SGN;
  cpx w1O1 = make_float2(r * (O1.x - S * O1.y), r * (O1.y + S * O1.x));
  cpx w3O3 = make_float2(r * (-O3.x - S * O3.y), r * (S * O3.x - O3.y));
  cpx jO2 = mulJ<SGN>(O2);
  a[0] = cadd(E0, O0);   a[4] = csub(E0, O0);
  a[1] = cadd(E1, w1O1); a[5] = csub(E1, w1O1);
  a[2] = cadd(E2, jO2);  a[6] = csub(E2, jO2);
  a[3] = cadd(E3, w3O3); a[7] = csub(E3, w3O3);
}

template <int SGN>
__device__ __forceinline__ void dft4(cpx b[4]) {
  cpx s0 = cadd(b[0], b[2]), d0 = csub(b[0], b[2]);
  cpx s1 = cadd(b[1], b[3]), d1 = csub(b[1], b[3]);
  cpx jd1 = mulJ<SGN>(d1);
  b[0] = cadd(s0, s1); b[2] = csub(s0, s1);
  b[1] = cadd(d0, jd1); b[3] = csub(d0, jd1);
}

__device__ __forceinline__ void twid8(cpx a[8], float ang) {
  float s, c; __sincosf(ang, &s, &c);
  cpx w1 = make_float2(c, s);
  cpx w2 = cmul(w1, w1), w3 = cmul(w2, w1), w4 = cmul(w2, w2);
  cpx w5 = cmul(w3, w2), w6 = cmul(w3, w3), w7 = cmul(w4, w3);
  a[1] = cmul(a[1], w1); a[2] = cmul(a[2], w2); a[3] = cmul(a[3], w3);
  a[4] = cmul(a[4], w4); a[5] = cmul(a[5], w5); a[6] = cmul(a[6], w6);
  a[7] = cmul(a[7], w7);
}

template <int SGN>
__device__ __forceinline__ void fft2048_core(cpx a[8], cpx* __restrict__ bufA,
                                             cpx* __restrict__ bufB, int t) {
  const float S = (float)SGN;
  dft8<SGN>(a);
  twid8(a, S * (2.f * PI_F / 2048.f) * (float)t);
#pragma unroll
  for (int p = 0; p < 8; ++p) bufA[p * 264 + t] = a[p];
  __syncthreads();
  int p = t >> 5, n1 = t & 31;
#pragma unroll
  for (int j = 0; j < 8; ++j) a[j] = bufA[p * 264 + n1 + 32 * j];
  dft8<SGN>(a);
  twid8(a, S * (2.f * PI_F / 256.f) * (float)n1);
#pragma unroll
  for (int q = 0; q < 8; ++q) bufB[p * 264 + q * 33 + n1] = a[q];
  __syncthreads();
  int q = (t >> 2) & 7, n2 = t & 3;
#pragma unroll
  for (int j = 0; j < 8; ++j) a[j] = bufB[p * 264 + q * 33 + n2 + 4 * j];
  dft8<SGN>(a);
  twid8(a, S * (2.f * PI_F / 32.f) * (float)n2);
#pragma unroll
  for (int d = 0; d < 8; ++d) bufA[p * 264 + q * 33 + 4 * d + n2] = a[d];
  __syncthreads();
#pragma unroll
  for (int h = 0; h < 2; ++h) {
    int d = 2 * n2 + h;
    cpx b[4];
#pragma unroll
    for (int m = 0; m < 4; ++m) b[m] = bufA[p * 264 + q * 33 + 4 * d + m];
    dft4<SGN>(b);
    int kb = p + 8 * q + 64 * d;
#pragma unroll
    for (int c = 0; c < 4; ++c) bufB[SW(kb + 512 * c)] = b[c];
  }
  __syncthreads();
}

// ---------------- forward rfft-4096 -> packed bf16 hi/lo U2 (interleaved re/im rows) ----------------
// Packed layout: P[g][col][s], g = row>>3, s = row&7, 8 bf16 (16 B) per (g,col) chunk.
__global__ __launch_bounds__(256, 4) void fft_fwd_pack(const float* __restrict__ u,
                                                       unsigned short* __restrict__ Uph,
                                                       unsigned short* __restrict__ Upl) {
  __shared__ cpx bufA[2112], bufB[2112];
  int t = threadIdx.x;
  int row = blockIdx.x;
  int b = row >> 7, q = row & 127;
  const cpx* src = (const cpx*)(u + (size_t)row * NL);
  cpx a[8];
#pragma unroll
  for (int j = 0; j < 8; ++j) a[j] = src[t + 256 * j];
  fft2048_core<-1>(a, bufA, bufB, t);
  size_t colb = (size_t)b * WB;
  size_t gbase = ((size_t)(q >> 2) * NT) * 8 + 2 * (q & 3);
  auto pstore = [&](int k, float ur, float ui) {
    size_t idx = gbase + (colb + k) * 8;
    unsigned short h0 = f2bf(ur), h1 = f2bf(ui);
    unsigned short l0 = f2bf(ur - bf2f(h0)), l1 = f2bf(ui - bf2f(h1));
    *(unsigned int*)&Uph[idx] = (unsigned int)h0 | ((unsigned int)h1 << 16);
    *(unsigned int*)&Upl[idx] = (unsigned int)l0 | ((unsigned int)l1 << 16);
  };
#pragma unroll
  for (int r = 0; r < 4; ++r) {
    int k = t + (r << 8);
    if (k == 0) {
      cpx z0 = bufB[SW(0)];
      pstore(0, z0.x + z0.y, 0.f);
      pstore(2048, z0.x - z0.y, 0.f);
      cpx zN = bufB[SW(1024)];
      pstore(1024, zN.x, -zN.y);
    } else {
      cpx A = bufB[SW(k)];
      cpx M = bufB[SW(2048 - k)];
      float Br = M.x, Bi = -M.y;
      float sr = 0.5f * (A.x + Br), si = 0.5f * (A.y + Bi);
      float dr = 0.5f * (A.x - Br), di = 0.5f * (A.y - Bi);
      float th = (float)k * (PI_F / 2048.f);
      float sn, cs; __sincosf(th, &sn, &cs);
      float tr = cs * dr + sn * di;
      float ti = cs * di - sn * dr;
      pstore(k, sr + ti, si - tr);
      float A2r = M.x, A2i = M.y;
      float B2r = A.x, B2i = -A.y;
      float s2r = 0.5f * (A2r + B2r), s2i = 0.5f * (A2i + B2i);
      float d2r = 0.5f * (A2r - B2r), d2i = 0.5f * (A2i - B2i);
      float t2r = -cs * d2r + sn * d2i;
      float t2i = -cs * d2i - sn * d2r;
      pstore(2048 - k, s2r + t2i, s2i - t2r);
    }
  }
}

// ---------------- GEMM1: V2 = Mb x U2 (split-bf16, 3 MFMA), scale, packed store ----------------
// Block 256 thr = 4 waves; tile 128 rows x 64 cols; BK=32. LDS 24 KB.
__global__ __launch_bounds__(256) void gemm1(
    const unsigned short* __restrict__ Mbh, const unsigned short* __restrict__ Mbl,
    const unsigned short* __restrict__ Uph, const unsigned short* __restrict__ Upl,
    const float* __restrict__ Lam,
    unsigned short* __restrict__ Vph, unsigned short* __restrict__ Vpl) {
  __shared__ unsigned short Ah[4096], Al[4096], Bh[2048], Bl[2048];
  int tid = threadIdx.x;
  int i0 = blockIdx.x * 128;
  int j0 = blockIdx.y * 64;
  int w = tid >> 6, lane = tid & 63, quad = lane >> 4, ln = lane & 15;
  int mw = w & 1, nw = w >> 1;
  f4 acc[4][2];
#pragma unroll
  for (int mt = 0; mt < 4; ++mt)
#pragma unroll
    for (int nt = 0; nt < 2; ++nt) acc[mt][nt] = (f4){0.f, 0.f, 0.f, 0.f};

  for (int kt = 0; kt < 256; kt += 32) {
    __syncthreads();
#pragma unroll
    for (int r = 0; r < 2; ++r) {
      int j = tid + 256 * r; int m = j >> 2, cch = j & 3;
      int slot = (m * 4 + (cch ^ (m & 3))) * 8;   // XOR swizzle vs bank conflicts
      size_t go = (size_t)(i0 + m) * 256 + kt + cch * 8;
      *(uint4*)&Ah[slot] = *(const uint4*)&Mbh[go];
      *(uint4*)&Al[slot] = *(const uint4*)&Mbl[go];
    }
    {
      int g = tid >> 6, n = tid & 63;
      size_t go = ((size_t)((kt >> 3) + g) * NT + (j0 + n)) * 8;
      *(uint4*)&Bh[tid * 8] = *(const uint4*)&Uph[go];
      *(uint4*)&Bl[tid * 8] = *(const uint4*)&Upl[go];
    }
    __syncthreads();
    bf8v ah[4], al[4], bh[2], bl[2];
#pragma unroll
    for (int mt = 0; mt < 4; ++mt) {
      int m = mw * 64 + mt * 16 + ln;
      int off = (m * 4 + (quad ^ (m & 3))) * 8;
      ah[mt] = *(const bf8v*)&Ah[off];
      al[mt] = *(const bf8v*)&Al[off];
    }
#pragma unroll
    for (int nt = 0; nt < 2; ++nt) {
      int off = (quad * 64 + nw * 32 + nt * 16 + ln) * 8;
      bh[nt] = *(const bf8v*)&Bh[off];
      bl[nt] = *(const bf8v*)&Bl[off];
    }
#pragma unroll
    for (int mt = 0; mt < 4; ++mt)
#pragma unroll
      for (int nt = 0; nt < 2; ++nt) {
        acc[mt][nt] = MFMA16(ah[mt], bh[nt], acc[mt][nt]);
        acc[mt][nt] = MFMA16(ah[mt], bl[nt], acc[mt][nt]);
        acc[mt][nt] = MFMA16(al[mt], bh[nt], acc[mt][nt]);
      }
  }
  // epilogue: Cauchy-kernel scale (re/im pairs are lane-local), packed bf16 store
#pragma unroll
  for (int mt = 0; mt < 4; ++mt) {
    int r0 = i0 + mw * 64 + mt * 16 + quad * 4;   // multiple of 4
    int p0 = r0 >> 1;                              // even
    float2 lam0 = ((const float2*)Lam)[p0];
    float2 lam1 = ((const float2*)Lam)[p0 + 1];
#pragma unroll
    for (int nt = 0; nt < 2; ++nt) {
      int col = j0 + nw * 32 + nt * 16 + ln;
      int bb = col / WB; int l = col - bb * WB;
      float omega = (float)l * (PI_F / 2048.f);
      f4 a = acc[mt][nt];
      float dx0 = -lam0.x, dy0 = omega - lam0.y;
      float inv0 = 1.f / (dx0 * dx0 + dy0 * dy0);
      float kr0 = dx0 * inv0, ki0 = -dy0 * inv0;
      float v0r = kr0 * a[0] - ki0 * a[1];
      float v0i = kr0 * a[1] + ki0 * a[0];
      float dx1 = -lam1.x, dy1 = omega - lam1.y;
      float inv1 = 1.f / (dx1 * dx1 + dy1 * dy1);
      float kr1 = dx1 * inv1, ki1 = -dy1 * inv1;
      float v1r = kr1 * a[2] - ki1 * a[3];
      float v1i = kr1 * a[3] + ki1 * a[2];
      size_t idx = ((size_t)(r0 >> 3) * NT + col) * 8 + (r0 & 7);
      unsigned short h0 = f2bf(v0r), h1 = f2bf(v0i), h2 = f2bf(v1r), h3 = f2bf(v1i);
      ushort4 H = {h0, h1, h2, h3};
      ushort4 L = {f2bf(v0r - bf2f(h0)), f2bf(v0i - bf2f(h1)),
                   f2bf(v1r - bf2f(h2)), f2bf(v1i - bf2f(h3))};
      *(ushort4*)&Vph[idx] = H;
      *(ushort4*)&Vpl[idx] = L;
    }
  }
}

// ---------------- GEMM2: Y2 = Mc x [V2'; U2], fp32 planar output ----------------
__global__ __launch_bounds__(256) void gemm2(
    const unsigned short* __restrict__ Mch, const unsigned short* __restrict__ Mcl,
    const unsigned short* __restrict__ Vph, const unsigned short* __restrict__ Vpl,
    const unsigned short* __restrict__ Uph, const unsigned short* __restrict__ Upl,
    float* __restrict__ Yo) {
  __shared__ unsigned short Ah[4096], Al[4096], Bh[2048], Bl[2048];
  int tid = threadIdx.x;
  int i0 = blockIdx.x * 128;
  int j0 = blockIdx.y * 64;
  int w = tid >> 6, lane = tid & 63, quad = lane >> 4, ln = lane & 15;
  int mw = w & 1, nw = w >> 1;
  f4 acc[4][2];
#pragma unroll
  for (int mt = 0; mt < 4; ++mt)
#pragma unroll
    for (int nt = 0; nt < 2; ++nt) acc[mt][nt] = (f4){0.f, 0.f, 0.f, 0.f};

  for (int kt = 0; kt < 512; kt += 32) {
    __syncthreads();
#pragma unroll
    for (int r = 0; r < 2; ++r) {
      int j = tid + 256 * r; int m = j >> 2, cch = j & 3;
      int slot = (m * 4 + (cch ^ (m & 3))) * 8;
      size_t go = (size_t)(i0 + m) * 512 + kt + cch * 8;
      *(uint4*)&Ah[slot] = *(const uint4*)&Mch[go];
      *(uint4*)&Al[slot] = *(const uint4*)&Mcl[go];
    }
    {
      const unsigned short* Sh = (kt < 256) ? Vph : Uph;
      const unsigned short* Sl = (kt < 256) ? Vpl : Upl;
      int g0 = (kt & 255) >> 3;
      int g = tid >> 6, n = tid & 63;
      size_t go = ((size_t)(g0 + g) * NT + (j0 + n)) * 8;
      *(uint4*)&Bh[tid * 8] = *(const uint4*)&Sh[go];
      *(uint4*)&Bl[tid * 8] = *(const uint4*)&Sl[go];
    }
    __syncthreads();
    bf8v ah[4], al[4], bh[2], bl[2];
#pragma unroll
    for (int mt = 0; mt < 4; ++mt) {
      int m = mw * 64 + mt * 16 + ln;
      int off = (m * 4 + (quad ^ (m & 3))) * 8;
      ah[mt] = *(const bf8v*)&Ah[off];
      al[mt] = *(const bf8v*)&Al[off];
    }
#pragma unroll
    for (int nt = 0; nt < 2; ++nt) {
      int off = (quad * 64 + nw * 32 + nt * 16 + ln) * 8;
      bh[nt] = *(const bf8v*)&Bh[off];
      bl[nt] = *(const bf8v*)&Bl[off];
    }
#pragma unroll
    for (int mt = 0; mt < 4; ++mt)
#pragma unroll
      for (int nt = 0; nt < 2; ++nt) {
        acc[mt][nt] = MFMA16(ah[mt], bh[nt], acc[mt][nt]);
        acc[mt][nt] = MFMA16(ah[mt], bl[nt], acc[mt][nt]);
        acc[mt][nt] = MFMA16(al[mt], bh[nt], acc[mt][nt]);
      }
  }
#pragma unroll
  for (int mt = 0; mt < 4; ++mt) {
    int r0 = i0 + mw * 64 + mt * 16 + quad * 4;
#pragma unroll
    for (int nt = 0; nt < 2; ++nt) {
      int col = j0 + nw * 32 + nt * 16 + ln;
      f4 a = acc[mt][nt];
#pragma unroll
      for (int rr = 0; rr < 4; ++rr)
        Yo[(size_t)(r0 + rr) * NT + col] = a[rr];
    }
  }
}

// ---------------- inverse rfft-4096 from fp32 planar Y2, fused exact GELU ----------------
__global__ __launch_bounds__(256, 4) void fft_inv_gelu_pl(const float* __restrict__ Y,
                                                          float* __restrict__ out) {
  __shared__ cpx bufA[2112], bufB[2112];
  int t = threadIdx.x;
  int row = blockIdx.x;
  int b = row >> 7, h = row & 127;
  const float* Yr = Y + (size_t)(2 * h) * NT + (size_t)b * WB;
  const float* Yi = Yr + NT;
#pragma unroll
  for (int r = 0; r < 4; ++r) {
    int k = t + (r << 8);
    if (k == 0) {
      float y0 = Yr[0];
      float yN = Yr[2048];
      bufB[SW(0)] = make_float2(0.5f * (y0 + yN), 0.5f * (y0 - yN));
      bufB[SW(1024)] = make_float2(Yr[1024], -Yi[1024]);
    } else {
      float Ar = Yr[k], Ai = Yi[k];
      float Mr = Yr[2048 - k], Mi = Yi[2048 - k];
      float Br = Mr, Bi = -Mi;
      float sr = 0.5f * (Ar + Br), si = 0.5f * (Ai + Bi);
      float dr = 0.5f * (Ar - Br), di = 0.5f * (Ai - Bi);
      float th = (float)k * (PI_F / 2048.f);
      float sn, cs; __sincosf(th, &sn, &cs);
      float e1 = cs * di + sn * dr;
      float e2 = cs * dr - sn * di;
      bufB[SW(k)] = make_float2(sr - e1, si + e2);
      bufB[SW(2048 - k)] = make_float2(sr + e1, -si + e2);
    }
  }
  __syncthreads();
  cpx a[8];
#pragma unroll
  for (int j = 0; j < 8; ++j) a[j] = bufB[SW(t + 256 * j)];
  fft2048_core<1>(a, bufA, bufB, t);
  float2* dst = (float2*)(out + (size_t)row * NL);
  const float sc = 1.f / 2048.f;
#pragma unroll
  for (int r = 0; r < 8; ++r) {
    int n = t + (r << 8);
    cpx z = bufB[SW(n)];
    dst[n] = make_float2(gelu_exact(z.x * sc), gelu_exact(z.y * sc));
  }
}

// ================= FALLBACK (R4 path, used only if ws too small) =================
__global__ __launch_bounds__(256, 4) void fb_fft_fwd(const float* __restrict__ u,
                                                     cpx* __restrict__ U) {
  __shared__ cpx bufA[2112], bufB[2112];
  int t = threadIdx.x;
  int row = blockIdx.x;
  const cpx* src = (const cpx*)(u + (size_t)row * NL);
  cpx a[8];
#pragma unroll
  for (int j = 0; j < 8; ++j) a[j] = src[t + 256 * j];
  fft2048_core<-1>(a, bufA, bufB, t);
  cpx* Urow = U + (size_t)row * LF;
#pragma unroll
  for (int r = 0; r < 4; ++r) {
    int k = t + (r << 8);
    if (k == 0) {
      cpx z0 = bufB[SW(0)];
      Urow[0] = make_float2(z0.x + z0.y, 0.f);
      Urow[2048] = make_float2(z0.x - z0.y, 0.f);
      cpx zN = bufB[SW(1024)];
      Urow[1024] = make_float2(zN.x, -zN.y);
    } else {
      cpx A = bufB[SW(k)];
      cpx M = bufB[SW(2048 - k)];
      float Br = M.x, Bi = -M.y;
      float sr = 0.5f * (A.x + Br), si = 0.5f * (A.y + Bi);
      float dr = 0.5f * (A.x - Br), di = 0.5f * (A.y - Bi);
      float th = (float)k * (PI_F / 2048.f);
      float sn, cs; __sincosf(th, &sn, &cs);
      float tr = cs * dr + sn * di;
      float ti = cs * di - sn * dr;
      Urow[k] = make_float2(sr + ti, si - tr);
      float A2r = M.x, A2i = M.y;
      float B2r = A.x, B2i = -A.y;
      float s2r = 0.5f * (A2r + B2r), s2i = 0.5f * (A2i + B2i);
      float d2r = 0.5f * (A2r - B2r), d2i = 0.5f * (A2i - B2i);
      float t2r = -cs * d2r + sn * d2i;
      float t2i = -cs * d2i - sn * d2r;
      Urow[2048 - k] = make_float2(s2r + t2i, s2i - t2r);
    }
  }
}

__device__ __forceinline__ void ld4(float4 d[4], const float4* __restrict__ p) {
#pragma unroll
  for (int kk = 0; kk < 4; ++kk) d[kk] = p[kk];
}
__device__ __forceinline__ void cmac4(const float4 m[4], float xr, float xi,
                                      float ar[8], float ai[8]) {
#pragma unroll
  for (int kk = 0; kk < 4; ++kk) {
    float4 v = m[kk];
    ar[2 * kk]     = fmaf(v.x, xr, fmaf(-v.y, xi, ar[2 * kk]));
    ai[2 * kk]     = fmaf(v.x, xi, fmaf( v.y, xr, ai[2 * kk]));
    ar[2 * kk + 1] = fmaf(v.z, xr, fmaf(-v.w, xi, ar[2 * kk + 1]));
    ai[2 * kk + 1] = fmaf(v.z, xi, fmaf( v.w, xr, ai[2 * kk + 1]));
  }
}

__global__ __launch_bounds__(256, 4) void fb_mix(
    const cpx* __restrict__ U,
    const float* __restrict__ Bt, const float* __restrict__ Ct,
    const float* __restrict__ Dt, const float* __restrict__ Lam,
    cpx* __restrict__ Y) {
  __shared__ cpx sU[128][17], sV[128][17];
  int tid = threadIdx.x;
  int b = blockIdx.y;
  size_t ub = (size_t)b * NH * LF;
  if (blockIdx.x == 128) {
    int t = tid;
    if (t < 128) sU[t][0] = U[ub + (size_t)t * LF + 2048];
    __syncthreads();
    if (t < 128) {
      float ar = 0.f, ai = 0.f;
      for (int q = 0; q < 128; ++q) {
        float ur = sU[q][0].x, ui = sU[q][0].y;
        float br = Bt[(q * 128 + t) * 2], bi = Bt[(q * 128 + t) * 2 + 1];
        ar = fmaf(br, ur, fmaf(-bi, ui, ar));
        ai = fmaf(br, ui, fmaf(bi, ur, ai));
      }
      float a = Lam[2 * t], bb = Lam[2 * t + 1];
      float dx = -a, dy = PI_F - bb;
      float inv = 1.f / (dx * dx + dy * dy);
      float kr = dx * inv, ki = -dy * inv;
      sV[t][0] = make_float2(kr * ar - ki * ai, kr * ai + ki * ar);
    }
    __syncthreads();
    if (t < 128) {
      float ar = 0.f, ai = 0.f;
      for (int q = 0; q < 128; ++q) {
        float ur = sU[q][0].x, ui = sU[q][0].y;
        float vr = sV[q][0].x, vi = sV[q][0].y;
        float cr = Ct[(q * 128 + t) * 2], ci = Ct[(q * 128 + t) * 2 + 1];
        float dr = Dt[(q * 128 + t) * 2], di = Dt[(q * 128 + t) * 2 + 1];
        ar += cr * vr - ci * vi + dr * ur - di * ui;
        ai += cr * vi + ci * vr + dr * ui + di * ur;
      }
      Y[ub + (size_t)t * LF + 2048] = make_float2(ar, ai);
    }
    return;
  }
  int lane = tid & 15, g = tid >> 4;
  int l = blockIdx.x * 16 + lane;
#pragma unroll
  for (int rep = 0; rep < 8; ++rep) {
    int q = rep * 16 + g;
    sU[q][lane] = U[ub + (size_t)q * LF + l];
  }
  __syncthreads();
  float omega = (float)l * (PI_F / 2048.f);
  float ar[8], ai[8];
  {
#pragma unroll
    for (int k = 0; k < 8; ++k) { ar[k] = 0.f; ai[k] = 0.f; }
    const float4* base = (const float4*)Bt + g * 4;
    float4 e[4], o[4];
    ld4(e, base);
#pragma unroll 1
    for (int q = 0; q < 128; q += 2) {
      ld4(o, base + (q + 1) * 64);
      cpx u0 = sU[q][lane];
      cmac4(e, u0.x, u0.y, ar, ai);
      ld4(e, base + ((q + 2) & 127) * 64);
      cpx u1 = sU[q + 1][lane];
      cmac4(o, u1.x, u1.y, ar, ai);
    }
    int p0 = g * 8;
#pragma unroll
    for (int k = 0; k < 8; ++k) {
      int p = p0 + k;
      float a = Lam[2 * p], bb = Lam[2 * p + 1];
      float dx = -a, dy = omega - bb;
      float inv = 1.f / (dx * dx + dy * dy);
      float kr = dx * inv, ki = -dy * inv;
      sV[p][lane] = make_float2(kr * ar[k] - ki * ai[k], kr * ai[k] + ki * ar[k]);
    }
  }
  __syncthreads();
  {
#pragma unroll
    for (int k = 0; k < 8; ++k) { ar[k] = 0.f; ai[k] = 0.f; }
    const float4* base = (const float4*)Ct + g * 4;
    float4 e[4], o[4];
    ld4(e, base);
#pragma unroll 1
    for (int q = 0; q < 128; q += 2) {
      ld4(o, base + (q + 1) * 64);
      cpx v0 = sV[q][lane];
      cmac4(e, v0.x, v0.y, ar, ai);
      ld4(e, base + ((q + 2) & 127) * 64);
      cpx v1 = sV[q + 1][lane];
      cmac4(o, v1.x, v1.y, ar, ai);
    }
  }
  {
    const float4* base = (const float4*)Dt + g * 4;
    float4 e[4], o[4];
    ld4(e, base);
#pragma unroll 1
    for (int q = 0; q < 128; q += 2) {
      ld4(o, base + (q + 1) * 64);
      cpx u0 = sU[q][lane];
      cmac4(e, u0.x, u0.y, ar, ai);
      ld4(e, base + ((q + 2) & 127) * 64);
      cpx u1 = sU[q + 1][lane];
      cmac4(o, u1.x, u1.y, ar, ai);
    }
  }
  int h0 = g * 8;
#pragma unroll
  for (int k = 0; k < 8; ++k) {
    Y[ub + (size_t)(h0 + k) * LF + l] = make_float2(ar[k], ai[k]);
  }
}

__global__ __launch_bounds__(256, 4) void fb_fft_inv(const cpx* __restrict__ Y,
                                                     float* __restrict__ out) {
  __shared__ cpx bufA[2112], bufB[2112];
  int t = threadIdx.x;
  int row = blockIdx.x;
  const cpx* Yrow = Y + (size_t)row * LF;
#pragma unroll
  for (int r = 0; r < 4; ++r) {
    int k = t + (r << 8);
    if (k == 0) {
      float y0 = Yrow[0].x;
      float yN = Yrow[2048].x;
      bufB[SW(0)] = make_float2(0.5f * (y0 + yN), 0.5f * (y0 - yN));
      cpx z = Yrow[1024];
      bufB[SW(1024)] = make_float2(z.x, -z.y);
    } else {
      cpx A = Yrow[k];
      cpx M = Yrow[2048 - k];
      float Br = M.x, Bi = -M.y;
      float sr = 0.5f * (A.x + Br), si = 0.5f * (A.y + Bi);
      float dr = 0.5f * (A.x - Br), di = 0.5f * (A.y - Bi);
      float th = (float)k * (PI_F / 2048.f);
      float sn, cs; __sincosf(th, &sn, &cs);
      float e1 = cs * di + sn * dr;
      float e2 = cs * dr - sn * di;
      bufB[SW(k)] = make_float2(sr - e1, si + e2);
      bufB[SW(2048 - k)] = make_float2(sr + e1, -si + e2);
    }
  }
  __syncthreads();
  cpx a[8];
#pragma unroll
  for (int j = 0; j < 8; ++j) a[j] = bufB[SW(t + 256 * j)];
  fft2048_core<1>(a, bufA, bufB, t);
  float2* dst = (float2*)(out + (size_t)row * NL);
  const float sc = 1.f / 2048.f;
#pragma unroll
  for (int r = 0; r < 8; ++r) {
    int n = t + (r << 8);
    cpx z = bufB[SW(n)];
    dst[n] = make_float2(gelu_exact(z.x * sc), gelu_exact(z.y * sc));
  }
}

extern "C" void kernel_launch(void* const* d_in, const int* in_sizes, int n_in,
                              void* d_out, int out_size, void* d_ws, size_t ws_size,
                              hipStream_t stream) {
  const float* u   = (const float*)d_in[0];
  const float* C2  = (const float*)d_in[1];
  const float* B2  = (const float*)d_in[2];
  const float* D   = (const float*)d_in[3];
  const float* Lam = (const float*)d_in[4];
  float* out = (float*)d_out;

  const size_t PACK = (size_t)32 * NT * 8;            // ushort elems per packed array
  const size_t need = PACK * 4 * 2                    // U/V packed hi+lo (bf16)
                    + (size_t)256 * NT * 4            // Y fp32 planar
                    + 4 * 32768 * 4                   // Bt, Ct, Dt, Tt fp32
                    + 2 * 65536 * 2 + 2 * 131072 * 2; // Mb, Mc bf16 hi/lo

  if (ws_size >= need) {
    unsigned short* Uph = (unsigned short*)d_ws;
    unsigned short* Upl = Uph + PACK;
    unsigned short* Vph = Upl + PACK;
    unsigned short* Vpl = Vph + PACK;
    float* Y  = (float*)(Vpl + PACK);
    float* Bt = Y + (size_t)256 * NT;
    float* Ct = Bt + 32768;
    float* Dt = Ct + 32768;
    float* Tt = Dt + 32768;
    unsigned short* Mbh = (unsigned short*)(Tt + 32768);
    unsigned short* Mbl = Mbh + 65536;
    unsigned short* Mch = Mbl + 65536;
    unsigned short* Mcl = Mch + 131072;

    precomp1<<<dim3(128, 3), 128, 0, stream>>>(C2, B2, D, Bt, Ct, Tt);
    precomp2<<<128, 128, 0, stream>>>(Tt, Dt);
    pack_mats<<<256, 256, 0, stream>>>(Bt, Ct, Dt, Mbh, Mbl, Mch, Mcl);
    fft_fwd_pack<<<NB * NH, 256, 0, stream>>>(u, Uph, Upl);
    gemm1<<<dim3(2, NT / 64), 256, 0, stream>>>(Mbh, Mbl, Uph, Upl, Lam, Vph, Vpl);
    gemm2<<<dim3(2, NT / 64), 256, 0, stream>>>(Mch, Mcl, Vph, Vpl, Uph, Upl, Y);
    fft_inv_gelu_pl<<<NB * NH, 256, 0, stream>>>(Y, out);
  } else {
    // fallback: R4 path (U aliased with Y; verified passing)
    float* ws = (float*)d_ws;
    const size_t nUc = (size_t)NB * NH * LF;
    cpx* U  = (cpx*)ws;
    cpx* Yp = U;
    float* Bt = ws + 2 * nUc;
    float* Ct = Bt + 32768;
    float* Dt = Ct + 32768;
    float* Tt = Dt + 32768;
    precomp1<<<dim3(128, 3), 128, 0, stream>>>(C2, B2, D, Bt, Ct, Tt);
    precomp2<<<128, 128, 0, stream>>>(Tt, Dt);
    fb_fft_fwd<<<NB * NH, 256, 0, stream>>>(u, U);
    fb_mix<<<dim3(129, NB), 256, 0, stream>>>(U, Bt, Ct, Dt, Lam, Yp);
    fb_fft_inv<<<NB * NH, 256, 0, stream>>>(Yp, out);
  }
}